// Round 9
// baseline (329.067 us; speedup 1.0000x reference)
//
#include <hip/hip_runtime.h>

// ---------------------------------------------------------------------------
// MultiScaleRetention on MI355X (gfx950).  Harness contract: inputs fp32,
// d_out read as fp32; detect() keeps it robust to a bf16 harness variant.
// Internal buffers are ALWAYS bf16 (r5 lesson).
//
// r6 chunkwise-state retention; r7 fine-chunk colsum scan; r9 wtrans bf16
// [N][K] weights; r11 XCD swizzle + occupancy; r12 gload_lds GEMM staging +
// coalesced epilogues; r13 BN=64 GEMM grid + retention2 gload/async-V (296us).
// r14: occupancy round (all kernels were latency-bound with idle pipes):
//  - retention2 LDS 64->48KB -> 3 blocks/CU: S staged in two K-halves via a
//    16KB buffer; Ps lives in Qs rows 0-63 (dead after their own QK^T:
//    th0 reads rows 0-63, th1 reads 64-127); O-epilogue stages through Qs.
//  - chunkstate LDS 64->32KB -> 4 blocks/CU: XT/XTs staged in two t-halves
//    (K-split, same accumulator); epilogue via 16KB XT in two row-halves.
//  - gemm128 launch_bounds (256,4)->(256,6): VGPR 64, LDS 24KB -> 6 blocks.
//
// ws ~38 MB: flag | X 16.8MB | U 256KB | WqkvT 256KB | WgT 2MB | WoT 2MB |
// qb 16.8MB (optional).  d_out: [0,16MB) Rb; [16,32MB) Carry then G/S.
// ---------------------------------------------------------------------------

constexpr int SEQ  = 2048;
constexpr int BATCH= 4;
constexpr int DIM  = 1024;
constexpr int HDIM = 128;
constexpr int NH   = 8;
constexpr int NBH  = BATCH * NH;   // 32
constexpr int NC   = 16;           // chunks of 128 along SEQ (state path)
constexpr int CCH  = 32;           // fine chunk for the colsum scan
constexpr int NCC  = SEQ / CCH;    // 64

typedef __bf16 bf16x8 __attribute__((ext_vector_type(8)));
typedef float  f32x4  __attribute__((ext_vector_type(4)));

__device__ __forceinline__ f32x4 mfma16(bf16x8 a, bf16x8 b, f32x4 c) {
  return __builtin_amdgcn_mfma_f32_16x16x32_bf16(a, b, c, 0, 0, 0);
}

__device__ __forceinline__ float bf2f(unsigned short u) {
  return __builtin_bit_cast(float, (unsigned int)u << 16);
}
__device__ __forceinline__ unsigned short f2bf(float f) {
  unsigned int x = __builtin_bit_cast(unsigned int, f);
  x += 0x7fffu + ((x >> 16) & 1u);   // RNE (finite inputs)
  return (unsigned short)(x >> 16);
}

// XOR-swizzled LDS element index for bf16 tiles. RS = row stride (64 or 128).
// Col-block permutation cb -> (cb&8)|((cb^(row>>1))&7) is an involution.
__device__ __forceinline__ int swz(int row, int col, int RS) {
  int cb  = col >> 3;
  int scb = (cb & ~7) | ((cb ^ (row >> 1)) & 7);
  return row * RS + scb * 8 + (col & 7);
}

// global -> LDS direct 16B load (dest = wave-uniform base + lane*16)
typedef const __attribute__((address_space(1))) unsigned int* gas_t;
typedef __attribute__((address_space(3))) unsigned int* las_t;
__device__ __forceinline__ void gl_lds16(const unsigned short* g, unsigned short* l) {
  __builtin_amdgcn_global_load_lds((gas_t)g, (las_t)l, 16, 0, 0);
}

// Pack 8 floats -> 8 bf16 (uint4)
__device__ __forceinline__ uint4 pack8(float4 a, float4 b) {
  uint4 o;
  o.x = (unsigned int)f2bf(a.x) | ((unsigned int)f2bf(a.y) << 16);
  o.y = (unsigned int)f2bf(a.z) | ((unsigned int)f2bf(a.w) << 16);
  o.z = (unsigned int)f2bf(b.x) | ((unsigned int)f2bf(b.y) << 16);
  o.w = (unsigned int)f2bf(b.z) | ((unsigned int)f2bf(b.w) << 16);
  return o;
}

// ---------------------------------------------------------------------------
// detect: flag=1 -> inputs bf16; flag=0 -> inputs fp32 (measured: 0 here).
// ---------------------------------------------------------------------------
__global__ void detect(const unsigned short* __restrict__ q, int* __restrict__ flag)
{
  int lane = threadIdx.x;              // 64
  int sane = 0;
  for (int i = lane; i < 1024; i += 64) {
    int e = (q[i] >> 7) & 0xFF;
    sane += (e >= 100 && e <= 140) ? 1 : 0;
  }
  #pragma unroll
  for (int o = 1; o < 64; o <<= 1) sane += __shfl_xor(sane, o);
  if (lane == 0) flag[0] = (sane >= 900) ? 1 : 0;
}

// ---------------------------------------------------------------------------
// qbf: qb = bf16(q), vectorized.  One uint4 (8 bf16) out per thread.
// ---------------------------------------------------------------------------
__global__ __launch_bounds__(256) void qbf(const void* __restrict__ q,
    unsigned short* __restrict__ qb, const int* __restrict__ dflag)
{
  const int idx = blockIdx.x * 256 + threadIdx.x;   // 1,048,576 granules of 8
  if (dflag[0]) {
    ((uint4*)qb)[idx] = ((const uint4*)q)[idx];
  } else {
    float4 a = ((const float4*)q)[2 * idx];
    float4 b = ((const float4*)q)[2 * idx + 1];
    ((uint4*)qb)[idx] = pack8(a, b);
  }
}

// ---------------------------------------------------------------------------
// wtrans: dst[n][k] = bf16(src[k][n]) for one (rows x cols) matrix, 64x64 LDS
// tiles.  blockIdx.z selects a matrix slice of rows*cols elems (Wqkv heads).
// ---------------------------------------------------------------------------
__global__ __launch_bounds__(256) void wtrans(const void* __restrict__ src,
    unsigned short* __restrict__ dst, int rows, int cols,
    const int* __restrict__ dflag)
{
  __shared__ float tile[64][65];
  const int isbf = dflag[0];
  const size_t moff = (size_t)blockIdx.z * rows * cols;
  const int r0 = blockIdx.y * 64, c0 = blockIdx.x * 64;
  const int tr = threadIdx.x >> 4;          // 0..15
  const int tc = (threadIdx.x & 15) * 4;    // 0,4,..,60

  #pragma unroll
  for (int rr = 0; rr < 64; rr += 16) {
    int r = r0 + rr + tr;
    if (isbf) {
      const unsigned short* s = (const unsigned short*)src + moff + (size_t)r * cols + c0 + tc;
      tile[rr + tr][tc + 0] = bf2f(s[0]);
      tile[rr + tr][tc + 1] = bf2f(s[1]);
      tile[rr + tr][tc + 2] = bf2f(s[2]);
      tile[rr + tr][tc + 3] = bf2f(s[3]);
    } else {
      float4 v = *(const float4*)((const float*)src + moff + (size_t)r * cols + c0 + tc);
      tile[rr + tr][tc + 0] = v.x;
      tile[rr + tr][tc + 1] = v.y;
      tile[rr + tr][tc + 2] = v.z;
      tile[rr + tr][tc + 3] = v.w;
    }
  }
  __syncthreads();

  const int n  = threadIdx.x >> 2;          // 0..63 (local dst row = src col)
  const int kg = (threadIdx.x & 3) * 16;    // 0,16,32,48
  unsigned int ov[8];
  #pragma unroll
  for (int j = 0; j < 8; ++j) {
    unsigned short lo = f2bf(tile[kg + 2 * j + 0][n]);
    unsigned short hi = f2bf(tile[kg + 2 * j + 1][n]);
    ov[j] = (unsigned int)lo | ((unsigned int)hi << 16);
  }
  unsigned short* d = dst + moff + (size_t)(c0 + n) * rows + r0 + kg;
  ((uint4*)d)[0] = make_uint4(ov[0], ov[1], ov[2], ov[3]);
  ((uint4*)d)[1] = make_uint4(ov[4], ov[5], ov[6], ov[7]);
}

// ---------------------------------------------------------------------------
// 128x64-tile MFMA GEMM, BK=64.  (256,6): 6 blocks/CU (24KB LDS, 64 VGPR).
// A: M x K (lda); adt 0=fp32 reg-staged, 1=bf16 gload_lds, 2=per input flag.
// B: ALWAYS internal bf16 [N][K] (ldb = K stride), gload_lds staged.
// mode 0: XCD-bijective block swizzle; bf16 out LDS-staged, fp32 out direct.
// mode 1 (head proj): z=head; A += z*128 cols; B += z*128*128; out bf16 ->
//   X[(b*8+z)*SEQ+s][HDIM], LDS-staged.
// ---------------------------------------------------------------------------
__global__ __launch_bounds__(256, 6) void gemm128(
    const void* __restrict__ A, int lda,
    const unsigned short* __restrict__ B, int ldb, int K,
    const void* __restrict__ bias, int act,
    void* __restrict__ out, int mode, int adt, int obf,
    const int* __restrict__ dflag)
{
  __shared__ __align__(16) unsigned short As[128 * 64];   // 16KB
  __shared__ __align__(16) unsigned short Bs[64 * 64];    // 8KB
  const int isbf = dflag[0];
  const int abf  = (adt == 1) || (adt == 2 && isbf);   // A is bf16?
  const int tid  = threadIdx.x;
  const int lane = tid & 63;
  const int w    = tid >> 6;
  const int wy   = w >> 1, wx = w & 1;
  const int m15  = lane & 15, qd = lane >> 4;
  // gload staging geometry
  const int w8  = w * 8;          // wave row base within a 32-row slab
  const int lr  = lane >> 3;      // row within wave slab (0..7)
  const int scb = lane & 7;       // dest col-block (linear LDS)

  int bx = blockIdx.x, by = blockIdx.y;
  if (mode == 0) {
    // XCD-bijective remap: XCD k owns a contiguous M-chunk.
    int nwg = gridDim.x * gridDim.y;   // 16*64 = 1024
    int lin = by * gridDim.x + bx;
    int qq = nwg >> 3, rr = nwg & 7;
    int xcd = lin & 7, idx = lin >> 3;
    int wg = (xcd < rr) ? xcd * (qq + 1) + idx
                        : rr * (qq + 1) + (xcd - rr) * qq + idx;
    bx = wg % gridDim.x;
    by = wg / gridDim.x;
  }

  const size_t aoff = (mode == 1) ? (size_t)blockIdx.z * 128 : 0;          // col offset
  const size_t boff = (mode == 1) ? (size_t)blockIdx.z * 128 * 128 : 0;    // elem offset
  const size_t arow = (size_t)(by * 128);
  const size_t bcol = (size_t)(bx * 64);

  f32x4 zero4 = {0.0f, 0.0f, 0.0f, 0.0f};
  f32x4 acc[4][2];
  #pragma unroll
  for (int i = 0; i < 4; ++i)
    #pragma unroll
    for (int j = 0; j < 2; ++j) acc[i][j] = zero4;

  const int kIters = K >> 6;
  for (int kt = 0; kt < kIters; ++kt) {
    __syncthreads();
    // ---- A staging: 128 rows x 64 k ----
    if (abf) {
      const unsigned short* pa = (const unsigned short*)A + aoff + arow * lda + kt * 64;
      #pragma unroll
      for (int g = 0; g < 4; ++g) {
        int r  = g * 32 + w8 + lr;
        int cb = scb ^ ((r >> 1) & 7);       // pre-swizzled source col-block
        gl_lds16(pa + (size_t)r * lda + cb * 8, &As[g * 2048 + w * 512]);
      }
    } else {
      const float* pa = (const float*)A + aoff + arow * lda + kt * 64;
      #pragma unroll
      for (int g = 0; g < 4; ++g) {
        int idx = tid + g * 256;
        int r = idx >> 3, cb = idx & 7;
        float4 f0 = *(const float4*)(pa + (size_t)r * lda + cb * 8);
        float4 f1 = *(const float4*)(pa + (size_t)r * lda + cb * 8 + 4);
        *(uint4*)&As[swz(r, cb * 8, 64)] = pack8(f0, f1);
      }
    }
    // ---- B staging: 64 rows x 64 k, [N][K] bf16, gload_lds ----
    {
      const unsigned short* pb = B + boff + bcol * (size_t)ldb + kt * 64;
      #pragma unroll
      for (int g = 0; g < 2; ++g) {
        int r  = g * 32 + w8 + lr;
        int cb = scb ^ ((r >> 1) & 7);
        gl_lds16(pb + (size_t)r * ldb + cb * 8, &Bs[g * 2048 + w * 512]);
      }
    }
    __syncthreads();
    #pragma unroll
    for (int kk = 0; kk < 2; ++kk) {
      bf16x8 af[4], bfr[2];
      #pragma unroll
      for (int mt = 0; mt < 4; ++mt)
        af[mt] = *(const bf16x8*)&As[swz(wy * 64 + mt * 16 + m15, kk * 32 + qd * 8, 64)];
      #pragma unroll
      for (int nt = 0; nt < 2; ++nt)
        bfr[nt] = *(const bf16x8*)&Bs[swz(wx * 32 + nt * 16 + m15, kk * 32 + qd * 8, 64)];
      #pragma unroll
      for (int mt = 0; mt < 4; ++mt)
        #pragma unroll
        for (int nt = 0; nt < 2; ++nt)
          acc[mt][nt] = mfma16(af[mt], bfr[nt], acc[mt][nt]);
    }
  }

  const int obf_eff = (obf == 2) ? (isbf ? 1 : 0) : obf;

  if (mode == 1 || obf_eff) {
    // bf16 output: LDS-staged coalesced epilogue ([128][64] = As, 16KB).
    __syncthreads();
    #pragma unroll
    for (int mt = 0; mt < 4; ++mt)
      #pragma unroll
      for (int nt = 0; nt < 2; ++nt) {
        int nl = wx * 32 + nt * 16 + m15;
        float bv = 0.0f;
        if (bias) {
          int n = bx * 64 + nl;
          bv = isbf ? bf2f(((const unsigned short*)bias)[n]) : ((const float*)bias)[n];
        }
        #pragma unroll
        for (int r = 0; r < 4; ++r) {
          int ml = wy * 64 + mt * 16 + qd * 4 + r;
          float v = acc[mt][nt][r] + bv;
          if (act == 1) v = v / (1.0f + __expf(-v));   // swish
          As[swz(ml, nl, 64)] = f2bf(v);
        }
      }
    __syncthreads();
    #pragma unroll
    for (int g = 0; g < 4; ++g) {
      int idx = tid + g * 256;               // 1024 granules of 16B
      int rr = idx >> 3, cbb = idx & 7;
      int m = by * 128 + rr;
      uint4 vv = *(const uint4*)&As[swz(rr, cbb * 8, 64)];
      if (mode == 1) {
        int b = m >> 11, s = m & 2047;
        size_t bh = (size_t)(b * NH + blockIdx.z);
        *(uint4*)&((unsigned short*)out)[(bh * SEQ + s) * HDIM + bx * 64 + cbb * 8] = vv;
      } else {
        *(uint4*)&((unsigned short*)out)[(size_t)m * (gridDim.x * 64) + bx * 64 + cbb * 8] = vv;
      }
    }
    return;
  }

  // fp32 output: direct stores (16 lanes x 4B = full 64B lines).
  #pragma unroll
  for (int mt = 0; mt < 4; ++mt)
    #pragma unroll
    for (int nt = 0; nt < 2; ++nt) {
      int nl = wx * 32 + nt * 16 + m15;
      int n  = bx * 64 + nl;
      float bv = 0.0f;
      if (bias) bv = isbf ? bf2f(((const unsigned short*)bias)[n]) : ((const float*)bias)[n];
      #pragma unroll
      for (int r = 0; r < 4; ++r) {
        int ml = wy * 64 + mt * 16 + qd * 4 + r;
        int m  = by * 128 + ml;
        float v = acc[mt][nt][r] + bv;
        if (act == 1) v = v / (1.0f + __expf(-v));   // swish
        ((float*)out)[(size_t)m * (gridDim.x * 64) + n] = v;
      }
    }
}

// ---------------------------------------------------------------------------
// kzcA: L[bh][cc][d] = sum_{i=0..31} g^i X[cc*32+i, d].
// ---------------------------------------------------------------------------
__global__ __launch_bounds__(128) void kzcA(const unsigned short* __restrict__ X,
                                            float* __restrict__ L)
{
  const int d  = threadIdx.x;            // 128
  const int cc = blockIdx.x;             // 64
  const int bh = blockIdx.y;             // 32
  const int h  = bh & 7;
  const float gam = 1.0f - exp2f(-5.0f - (float)h);
  const unsigned short* Xb = X + (size_t)bh * SEQ * HDIM + (size_t)cc * CCH * HDIM;
  float z = 0.0f;
  #pragma unroll
  for (int i = CCH - 1; i >= 0; --i)
    z = bf2f(Xb[(size_t)i * HDIM + d]) + gam * z;
  L[((size_t)bh * NCC + cc) * HDIM + d] = z;
}

// ---------------------------------------------------------------------------
// kzcB: in-place combine L -> Carry.  Carry[bh][cc][d] = Z_{(cc+1)*32}.
// ---------------------------------------------------------------------------
__global__ __launch_bounds__(128) void kzcB(float* __restrict__ L)
{
  const int d  = threadIdx.x;            // 128
  const int bh = blockIdx.x;             // 32
  const int h  = bh & 7;
  const float gam = 1.0f - exp2f(-5.0f - (float)h);
  const float g32 = exp2f(log2f(gam) * (float)CCH);
  float z = 0.0f;
  for (int cc = NCC - 1; cc >= 0; --cc) {
    size_t i = ((size_t)bh * NCC + cc) * HDIM + d;
    float lc = L[i];
    L[i] = z;                 // Carry[cc] = Z_{(cc+1)*32}
    z = lc + g32 * z;
  }
}

// ---------------------------------------------------------------------------
// kdot2: per (fine chunk of 32, bh) chunk-local suffix in regs, wave-reduced
// dot(X_t, Z_t) stashed in lane t; tail computed once across 32 lanes.
// Emits u_t = c1 / (sqrt(colD_t) * max(|colsum_t|,1)).
// ---------------------------------------------------------------------------
__global__ __launch_bounds__(64) void kdot2(const unsigned short* __restrict__ X,
    const float* __restrict__ Carry, float* __restrict__ U)
{
  const int lane = threadIdx.x;          // 64
  const int cc   = blockIdx.x;           // 64 fine chunks of 32
  const int bh   = blockIdx.y;
  const int h    = bh & 7;
  const float gam    = 1.0f - exp2f(-5.0f - (float)h);
  const float l2g    = log2f(gam);
  const float inv1mg = exp2f(5.0f + (float)h);          // 1/(1-g) exact
  const float c1     = 0.08838834764831845f;            // 1/sqrt(128)
  const unsigned short* Xb = X + (size_t)bh * SEQ * HDIM + (size_t)cc * CCH * HDIM;
  float2 cr = *(const float2*)(Carry + ((size_t)bh * NCC + cc) * HDIM + lane * 2);
  float z0 = 0.0f, z1 = 0.0f;
  float coeff = gam;                     // g^{(cc+1)*32 - t}
  float keep = 0.0f;
  #pragma unroll
  for (int i = 0; i < CCH; ++i) {
    const int t = CCH - 1 - i;           // descending local t
    unsigned int xu = *(const unsigned int*)(Xb + (size_t)t * HDIM + lane * 2);
    float x0 = bf2f((unsigned short)(xu & 0xffffu));
    float x1 = bf2f((unsigned short)(xu >> 16));
    z0 = x0 + gam * z0;                  // local suffix incl. x_t
    z1 = x1 + gam * z1;
    float dot = x0 * (z0 + coeff * cr.x) + x1 * (z1 + coeff * cr.y);
    #pragma unroll
    for (int o = 1; o < 64; o <<= 1) dot += __shfl_xor(dot, o);
    if (lane == t) keep = dot;
    coeff *= gam;
  }
  if (lane < CCH) {
    int tg = cc * CCH + lane;
    float colD   = (1.0f - exp2f(l2g * (float)(SEQ - tg))) * inv1mg;
    float sq     = sqrtf(colD);
    float colsum = keep * c1 / sq;
    float den    = fmaxf(fabsf(colsum), 1.0f);
    U[(size_t)bh * SEQ + tg] = c1 / (sq * den);
  }
}

// ---------------------------------------------------------------------------
// chunkstate: per (c, bh) compute G_c[d1,d2] = sum_{tl} g^{127-tl} u_t
// X[t,d1] X[t,d2], bf16 out.  r14: t staged in two 64-halves (K-split, same
// accumulator) -> LDS 32KB -> 4 blocks/CU; epilogue via 16KB XT half-passes.
// ---------------------------------------------------------------------------
__global__ __launch_bounds__(256, 4) void chunkstate(
    const unsigned short* __restrict__ X,
    const float* __restrict__ U,
    unsigned short* __restrict__ G)
{
  __shared__ __align__(16) unsigned short XT [8192];   // [128 d][64 t] RS=64
  __shared__ __align__(16) unsigned short XTs[8192];   // scaled copy
  const int tid  = threadIdx.x;
  const int lane = tid & 63;
  const int w    = tid >> 6;
  const int wy   = w >> 1, wx = w & 1;
  const int m15  = lane & 15, qd = lane >> 4;
  const int c    = blockIdx.x;           // 16
  const int bh   = blockIdx.y;           // 32
  const int h    = bh & 7;
  const float gam = 1.0f - exp2f(-5.0f - (float)h);
  const float l2g = log2f(gam);
  const int t0 = c * 128;
  const unsigned short* Xb = X + (size_t)bh * SEQ * HDIM;
  const float* Ub = U + (size_t)bh * SEQ;

  f32x4 zero4 = {0.0f, 0.0f, 0.0f, 0.0f};
  f32x4 acc[4][4];
  #pragma unroll
  for (int i = 0; i < 4; ++i)
    #pragma unroll
    for (int j = 0; j < 4; ++j) acc[i][j] = zero4;

  #pragma unroll
  for (int half = 0; half < 2; ++half) {
    if (half) __syncthreads();           // previous half's MFMA reads done
    #pragma unroll
    for (int g = 0; g < 4; ++g) {
      int idx = tid + g * 256;           // 1024 granules: 64 t x 16 d-blocks
      int t = idx >> 4, d0 = (idx & 15) * 8;
      int tg = half * 64 + t;
      uint4 w4 = *(const uint4*)(Xb + (size_t)(t0 + tg) * HDIM + d0);
      float wt = exp2f(l2g * (float)(127 - tg)) * Ub[t0 + tg];
      const unsigned short* wp = (const unsigned short*)&w4;
      #pragma unroll
      for (int j = 0; j < 8; ++j) {
        unsigned short v = wp[j];
        XT [swz(d0 + j, t, 64)] = v;
        XTs[swz(d0 + j, t, 64)] = f2bf(bf2f(v) * wt);
      }
    }
    __syncthreads();
    #pragma unroll
    for (int kk = 0; kk < 2; ++kk) {
      bf16x8 af[4], bfr[4];
      #pragma unroll
      for (int mt = 0; mt < 4; ++mt)
        af[mt] = *(const bf16x8*)&XTs[swz(wy * 64 + mt * 16 + m15, kk * 32 + qd * 8, 64)];
      #pragma unroll
      for (int nt = 0; nt < 4; ++nt)
        bfr[nt] = *(const bf16x8*)&XT[swz(wx * 64 + nt * 16 + m15, kk * 32 + qd * 8, 64)];
      #pragma unroll
      for (int mt = 0; mt < 4; ++mt)
        #pragma unroll
        for (int nt = 0; nt < 4; ++nt)
          acc[mt][nt] = mfma16(af[mt], bfr[nt], acc[mt][nt]);
    }
  }

  // Epilogue: two 64-row half-passes via XT ([64][128] = 16KB).
  unsigned short* Gp = G + (((size_t)bh * NC + c) << 14);
  #pragma unroll
  for (int h2 = 0; h2 < 2; ++h2) {
    __syncthreads();
    if (wy == h2) {
      #pragma unroll
      for (int mt = 0; mt < 4; ++mt)
        #pragma unroll
        for (int nt = 0; nt < 4; ++nt) {
          int d2 = wx * 64 + nt * 16 + m15;
          #pragma unroll
          for (int r = 0; r < 4; ++r) {
            int dl = mt * 16 + qd * 4 + r;
            XT[swz(dl, d2, 128)] = f2bf(acc[mt][nt][r]);
          }
        }
    }
    __syncthreads();
    #pragma unroll
    for (int g = 0; g < 4; ++g) {
      int idx = tid + g * 256;              // 1024 granules of 16B
      int rr = idx >> 4, cbb = idx & 15;
      *(uint4*)&Gp[(size_t)(h2 * 64 + rr) * 128 + cbb * 8] =
          *(const uint4*)&XT[swz(rr, cbb * 8, 128)];
    }
  }
}

// ---------------------------------------------------------------------------
// scanS: in-place prefix scan over chunks:  S_c = g^128 * S_{c-1} + G_c.
// ---------------------------------------------------------------------------
__global__ __launch_bounds__(256) void scanS(unsigned short* __restrict__ GS)
{
  int gid = blockIdx.x * 256 + threadIdx.x;    // 65536 total
  int bh = gid >> 11;
  int e8 = (gid & 2047) << 3;
  int h  = bh & 7;
  float gam  = 1.0f - exp2f(-5.0f - (float)h);
  float g128 = exp2f(log2f(gam) * 128.0f);
  float s[8];
  #pragma unroll
  for (int j = 0; j < 8; ++j) s[j] = 0.0f;
  unsigned short* base = GS + ((size_t)bh << 18) + e8;   // bh * 16 * 16384
  #pragma unroll
  for (int c = 0; c < NC; ++c) {
    uint4 v = *(uint4*)(base + ((size_t)c << 14));
    const unsigned short* wp = (const unsigned short*)&v;
    #pragma unroll
    for (int j = 0; j < 8; ++j) s[j] = g128 * s[j] + bf2f(wp[j]);
    uint4 o;
    unsigned int* op = (unsigned int*)&o;
    op[0] = (unsigned int)f2bf(s[0]) | ((unsigned int)f2bf(s[1]) << 16);
    op[1] = (unsigned int)f2bf(s[2]) | ((unsigned int)f2bf(s[3]) << 16);
    op[2] = (unsigned int)f2bf(s[4]) | ((unsigned int)f2bf(s[5]) << 16);
    op[3] = (unsigned int)f2bf(s[6]) | ((unsigned int)f2bf(s[7]) << 16);
    *(uint4*)(base + ((size_t)c << 14)) = o;
  }
}

// ---------------------------------------------------------------------------
// retention2: per (chunk c, bh), UNIFORM work:
//   cross: O = diag(g^{sl+1}) * X_s @ S_{c-1}; local masked triangle via LDS.
// r14: LDS 48KB -> 3 blocks/CU.  S staged in two K-halves through SB (16KB,
// [d2][d1half] RS=64, symmetric S so rows=d2 load contiguously); Ps lives in
// Qs rows 0-63 (dead after their QK^T: th0 reads rows 0-63, th1 rows 64-127);
// O-epilogue staged through Qs (fully dead by then).
// ---------------------------------------------------------------------------
__global__ __launch_bounds__(256, 3) void retention2(
    const unsigned short* __restrict__ X,
    const float* __restrict__ U,
    const unsigned short* __restrict__ S,
    unsigned short* __restrict__ R)
{
  __shared__ __align__(16) unsigned short Qs[16384];   // 32KB [128][128]
  __shared__ __align__(16) unsigned short SB[8192];    // 16KB S-half / VsT

  const int tid  = threadIdx.x;
  const int lane = tid & 63;
  const int w    = tid >> 6;
  const int wy   = w >> 1, wx = w & 1;
  const int m15  = lane & 15, qd = lane >> 4;
  const int c    = blockIdx.x;           // 16
  const int bh   = blockIdx.y;           // 32
  const int h    = bh & 7;
  const int b    = bh >> 3;
  const float gam = 1.0f - exp2f(-5.0f - (float)h);
  const float l2g = log2f(gam);
  const int sbase = c * 128;
  const unsigned short* Xb = X + (size_t)bh * SEQ * HDIM;
  const float* Ub = U + (size_t)bh * SEQ;
  const unsigned short* Sp = (c > 0) ? S + (((size_t)bh * NC + (c - 1)) << 14) : S;

  // ---- Qs staging via gload_lds (pre-swizzled source) ----
  {
    const int lr4 = lane >> 4;           // 0..3
    const int cbd = lane & 15;           // dest col-block
    #pragma unroll
    for (int g = 0; g < 8; ++g) {
      int r   = g * 16 + w * 4 + lr4;
      int cbs = (cbd & 8) | ((cbd ^ (r >> 1)) & 7);
      gl_lds16(Xb + (size_t)(sbase + r) * HDIM + cbs * 8, &Qs[(g * 16 + w * 4) * 128]);
    }
  }
  if (c > 0) {                           // S half 0: d1 in [0,64), SB[d2][d1]
    #pragma unroll
    for (int g = 0; g < 4; ++g) {
      int r  = g * 32 + w * 8 + (lane >> 3);     // d2 row
      int cb = (lane & 7) ^ ((r >> 1) & 7);      // pre-swizzled source block
      gl_lds16(Sp + (size_t)r * 128 + cb * 8, &SB[g * 2048 + w * 512]);
    }
  }
  // T14 early issue: th=0 V tile into registers (overlaps staging + cross).
  uint4 rvb[2][4];
  #pragma unroll
  for (int g = 0; g < 4; ++g) {
    int idx = tid + g * 256;
    int t = idx & 63, d0 = (idx >> 6) * 8;
    rvb[0][g] = *(const uint4*)(Xb + (size_t)(sbase + t) * HDIM + d0);
  }
  __syncthreads();

  bf16x8 aq[4][4];
  #pragma unroll
  for (int mt = 0; mt < 4; ++mt)
    #pragma unroll
    for (int kk = 0; kk < 4; ++kk)
      aq[mt][kk] = *(const bf16x8*)&Qs[swz(wy * 64 + mt * 16 + m15, kk * 32 + qd * 8, 128)];

  float crowL[16];                       // g^{sl}, sl = chunk-local row
  #pragma unroll
  for (int mt = 0; mt < 4; ++mt)
    #pragma unroll
    for (int r = 0; r < 4; ++r)
      crowL[mt * 4 + r] = exp2f(l2g * (float)(wy * 64 + mt * 16 + qd * 4 + r));

  f32x4 zero4 = {0.0f, 0.0f, 0.0f, 0.0f};
  f32x4 oacc[4][4];
  #pragma unroll
  for (int i = 0; i < 4; ++i)
    #pragma unroll
    for (int j = 0; j < 4; ++j) oacc[i][j] = zero4;

  if (c > 0) {                           // cross term: X_s @ S_{c-1}, K-halved
    #pragma unroll
    for (int kk = 0; kk < 2; ++kk) {     // d1 in [0,64)
      bf16x8 bs[4];
      #pragma unroll
      for (int nt = 0; nt < 4; ++nt)
        bs[nt] = *(const bf16x8*)&SB[swz(wx * 64 + nt * 16 + m15, kk * 32 + qd * 8, 64)];
      #pragma unroll
      for (int mt = 0; mt < 4; ++mt)
        #pragma unroll
        for (int nt = 0; nt < 4; ++nt)
          oacc[mt][nt] = mfma16(aq[mt][kk], bs[nt], oacc[mt][nt]);
    }
    __syncthreads();                     // half-0 reads done
    #pragma unroll
    for (int g = 0; g < 4; ++g) {        // S half 1: d1 in [64,128)
      int r  = g * 32 + w * 8 + (lane >> 3);
      int cb = (lane & 7) ^ ((r >> 1) & 7);
      gl_lds16(Sp + (size_t)r * 128 + 64 + cb * 8, &SB[g * 2048 + w * 512]);
    }
    __syncthreads();                     // half-1 ready (barrier drains vmcnt)
    #pragma unroll
    for (int kk = 0; kk < 2; ++kk) {
      bf16x8 bs[4];
      #pragma unroll
      for (int nt = 0; nt < 4; ++nt)
        bs[nt] = *(const bf16x8*)&SB[swz(wx * 64 + nt * 16 + m15, kk * 32 + qd * 8, 64)];
      #pragma unroll
      for (int mt = 0; mt < 4; ++mt)
        #pragma unroll
        for (int nt = 0; nt < 4; ++nt)
          oacc[mt][nt] = mfma16(aq[mt][2 + kk], bs[nt], oacc[mt][nt]);
    }
    #pragma unroll
    for (int mt = 0; mt < 4; ++mt) {     // scale cross by g^{sl+1}
      #pragma unroll
      for (int r = 0; r < 4; ++r) {
        float f = crowL[mt * 4 + r] * gam;
        #pragma unroll
        for (int nt = 0; nt < 4; ++nt) oacc[mt][nt][r] *= f;
      }
    }
  }

  unsigned short* VsT = SB;              // [128 d][64 t] RS=64 (16KB)
  unsigned short* Ps  = Qs;              // Qs rows 0-63 region (16KB), RS=64

  #pragma unroll
  for (int th = 0; th < 2; ++th) {
    const int t0 = th * 64;
    // local QK^T for this t-half: th0 reads Qs rows 0-63, th1 rows 64-127.
    f32x4 pacc[4][2];
    #pragma unroll
    for (int i = 0; i < 4; ++i) { pacc[i][0] = zero4; pacc[i][1] = zero4; }
    #pragma unroll
    for (int kk = 0; kk < 4; ++kk) {
      bf16x8 bk[2];
      #pragma unroll
      for (int nt = 0; nt < 2; ++nt)
        bk[nt] = *(const bf16x8*)&Qs[swz(t0 + wx * 32 + nt * 16 + m15, kk * 32 + qd * 8, 128)];
      #pragma unroll
      for (int mt = 0; mt < 4; ++mt)
        #pragma unroll
        for (int nt = 0; nt < 2; ++nt)
          pacc[mt][nt] = mfma16(aq[mt][kk], bk[nt], pacc[mt][nt]);
    }
    __syncthreads();                     // prior SB/Ps readers done

    // VsT write from pre-loaded registers: VsT[d][t] = X[t][d]
    #pragma unroll
    for (int g = 0; g < 4; ++g) {
      int idx = tid + g * 256;
      int t = idx & 63, d0 = (idx >> 6) * 8;
      const unsigned short* wp = (const unsigned short*)&rvb[th][g];
      #pragma unroll
      for (int j = 0; j < 8; ++j)
        VsT[swz(d0 + j, t, 64)] = wp[j];
    }
    if (th == 0) {                       // issue th=1 V loads (hide under P/PV)
      #pragma unroll
      for (int g = 0; g < 4; ++g) {
        int idx = tid + g * 256;
        int t = idx & 63, d0 = (idx >> 6) * 8;
        rvb[1][g] = *(const uint4*)(Xb + (size_t)(sbase + 64 + t) * HDIM + d0);
      }
    }
    // P = mask(s>=t) * pacc * g^{s-t} * u_t  -> bf16 into Qs rows 0-63
    #pragma unroll
    for (int nt = 0; nt < 2; ++nt) {
      int tloc = t0 + wx * 32 + nt * 16 + m15;
      float cf = exp2f(-l2g * (float)tloc) * Ub[sbase + tloc];   // g^{-tloc} u_t
      #pragma unroll
      for (int mt = 0; mt < 4; ++mt)
        #pragma unroll
        for (int r = 0; r < 4; ++r) {
          int sl = wy * 64 + mt * 16 + qd * 4 + r;
          float v = (sl >= tloc) ? pacc[mt][nt][r] * crowL[mt * 4 + r] * cf : 0.0f;
          Ps[swz(sl, tloc - t0, 64)] = f2bf(v);
        }
    }
    __syncthreads();
    // O += P @ V
    #pragma unroll
    for (int kk = 0; kk < 2; ++kk) {
      bf16x8 ap[4], bv[4];
      #pragma unroll
      for (int mt = 0; mt < 4; ++mt)
        ap[mt] = *(const bf16x8*)&Ps[swz(wy * 64 + mt * 16 + m15, kk * 32 + qd * 8, 64)];
      #pragma unroll
      for (int nt = 0; nt < 4; ++nt)
        bv[nt] = *(const bf16x8*)&VsT[swz(wx * 64 + nt * 16 + m15, kk * 32 + qd * 8, 64)];
      #pragma unroll
      for (int mt = 0; mt < 4; ++mt)
        #pragma unroll
        for (int nt = 0; nt < 4; ++nt)
          oacc[mt][nt] = mfma16(ap[mt], bv[nt], oacc[mt][nt]);
    }
  }

  // --- LDS-staged coalesced O write (Qs fully dead now) ---
  __syncthreads();
  #pragma unroll
  for (int mt = 0; mt < 4; ++mt)
    #pragma unroll
    for (int nt = 0; nt < 4; ++nt) {
      int n = wx * 64 + nt * 16 + m15;
      #pragma unroll
      for (int r = 0; r < 4; ++r) {
        int sl = wy * 64 + mt * 16 + qd * 4 + r;
        Qs[swz(sl, n, 128)] = f2bf(oacc[mt][nt][r]);
      }
    }
  __syncthreads();
  #pragma unroll
  for (int g = 0; g < 8; ++g) {
    int idx = tid + g * 256;               // 2048 granules of 16B
    int rr = idx >> 4, cbb = idx & 15;
    *(uint4*)&R[(size_t)(b * SEQ + sbase + rr) * DIM + h * HDIM + cbb * 8] =
        *(const uint4*)&Qs[swz(rr, cbb * 8, 128)];
  }
}

// ---------------------------------------------------------------------------
// GroupNorm(32 groups of 32 channels) + beta (per-flag dtype), gated; U
// written IN PLACE over G (ours, bf16).
// ---------------------------------------------------------------------------
__global__ __launch_bounds__(256) void gn_gate(const unsigned short* __restrict__ R,
    const void* __restrict__ beta, unsigned short* __restrict__ GU,
    const int* __restrict__ dflag)
{
  const int isbf = dflag[0];
  const int row = blockIdx.x;
  const int t   = threadIdx.x;
  uint2 xv = *(const uint2*)(R + (size_t)row * DIM + t * 4);
  float x0 = bf2f((unsigned short)(xv.x & 0xffffu)), x1 = bf2f((unsigned short)(xv.x >> 16));
  float x2 = bf2f((unsigned short)(xv.y & 0xffffu)), x3 = bf2f((unsigned short)(xv.y >> 16));
  float s  = x0 + x1 + x2 + x3;
  float ss = x0 * x0 + x1 * x1 + x2 * x2 + x3 * x3;
  #pragma unroll
  for (int m = 1; m <= 4; m <<= 1) {
    s  += __shfl_xor(s, m, 8);
    ss += __shfl_xor(ss, m, 8);
  }
  float mean = s * (1.0f / 32.0f);
  float var  = ss * (1.0f / 32.0f) - mean * mean;
  float rstd = rsqrtf(var + 1e-3f);
  float b0, b1, b2, b3;
  if (isbf) {
    uint2 bv = *(const uint2*)((const unsigned short*)beta + t * 4);
    b0 = bf2f((unsigned short)(bv.x & 0xffffu)); b1 = bf2f((unsigned short)(bv.x >> 16));
    b2 = bf2f((unsigned short)(bv.y & 0xffffu)); b3 = bf2f((unsigned short)(bv.y >> 16));
  } else {
    float4 bv = *(const float4*)((const float*)beta + t * 4);
    b0 = bv.x; b1 = bv.y; b2 = bv.z; b3 = bv.w;
  }
  uint2 gv = *(const uint2*)(GU + (size_t)row * DIM + t * 4);
  float g0 = bf2f((unsigned short)(gv.x & 0xffffu)), g1 = bf2f((unsigned short)(gv.x >> 16));
  float g2 = bf2f((unsigned short)(gv.y & 0xffffu)), g3 = bf2f((unsigned short)(gv.y >> 16));
  unsigned short u0 = f2bf(((x0 - mean) * rstd + b0) * g0);
  unsigned short u1 = f2bf(((x1 - mean) * rstd + b1) * g1);
  unsigned short u2 = f2bf(((x2 - mean) * rstd + b2) * g2);
  unsigned short u3 = f2bf(((x3 - mean) * rstd + b3) * g3);
  uint2 o;
  o.x = (unsigned int)u0 | ((unsigned int)u1 << 16);
  o.y = (unsigned int)u2 | ((unsigned int)u3 << 16);
  *(uint2*)(GU + (size_t)row * DIM + t * 4) = o;
}

// ---------------------------------------------------------------------------
extern "C" void kernel_launch(void* const* d_in, const int* in_sizes, int n_in,
                              void* d_out, int out_size, void* d_ws, size_t ws_size,
                              hipStream_t stream)
{
  (void)in_sizes; (void)n_in; (void)out_size;
  const void* q    = d_in[0];
  // d_in[1]=k, d_in[2]=v unused (reference uses q for Q,K,V)
  const void* Wqkv = d_in[3];
  const void* Wg   = d_in[4];
  const void* bg   = d_in[5];
  const void* Wo   = d_in[6];
  const void* bo   = d_in[7];
  const void* beta = d_in[8];

  char* p = (char*)d_ws;
  auto take = [&](size_t bytes) { char* r = p; p += (bytes + 255) & ~(size_t)255; return r; };
  int*  flag = (int*)take(256);
  unsigned short* X  = (unsigned short*)take((size_t)NBH * SEQ * HDIM * 2);  // 16.8 MB
  float* U     = (float*)take((size_t)NBH * SEQ * 4);                        // 256 KB
  unsigned short* WqkvT = (unsigned short*)take((size_t)NH * HDIM * HDIM * 2);   // 256 KB
  unsigned short* WgT   = (unsigned short*)take((size_t)DIM * DIM * 2);          // 2 MB
  unsigned short* WoT   = (unsigned short*)take((size_t)DIM * DIM * 2);          // 2 MB
  // Optional bf16 copy of q (enables gload_lds A staging everywhere).
  size_t qbBytes = (size_t)BATCH * SEQ * DIM * 2;                            // 16.8 MB
  unsigned short* qb = (unsigned short*)take(qbBytes);
  const bool useQb = ((size_t)(p - (char*)d_ws) <= ws_size);
  // Aliases (stream-ordered lifetimes):
  unsigned short* Rb = (unsigned short*)d_out;                          // [0,16MB)
  unsigned short* GS = (unsigned short*)((char*)d_out + (size_t)16 * 1024 * 1024); // [16,32MB)
  float* Carry = (float*)GS;   // 1MB at GS head, dead before chunkstate
  unsigned short* Gg = X;      // gate gemm output after retention2

  detect<<<1, 64, 0, stream>>>((const unsigned short*)q, flag);

  // Pre-transpose + convert weights to bf16 [N][K]; optional q -> bf16.
  wtrans<<<dim3(16, 16, 1), 256, 0, stream>>>(Wg,   WgT,   DIM,  DIM,  flag);
  wtrans<<<dim3(16, 16, 1), 256, 0, stream>>>(Wo,   WoT,   DIM,  DIM,  flag);
  wtrans<<<dim3(2, 2, NH),  256, 0, stream>>>(Wqkv, WqkvT, HDIM, HDIM, flag);
  if (useQb)
    qbf<<<4096, 256, 0, stream>>>(q, qb, flag);

  const void* Aq = useQb ? (const void*)qb : q;
  const int   adtq = useQb ? 1 : 2;

  // X = q_h @ W_h per head (N=128 per head -> 2 N-blocks of 64).
  gemm128<<<dim3(2, 64, NH), 256, 0, stream>>>(Aq, DIM, WqkvT, HDIM, HDIM,
                                               nullptr, 0, X, 1, adtq, /*obf*/1, flag);

  // Column-normalizer: 32-step local decayed sums, combine, per-chunk dot.
  kzcA <<<dim3(NCC, NBH), 128, 0, stream>>>(X, Carry);
  kzcB <<<NBH, 128, 0, stream>>>(Carry);
  kdot2<<<dim3(NCC, NBH), 64, 0, stream>>>(X, Carry, U);

  // Chunkwise state path: G_c -> (scan) -> S_c, then uniform retention blocks.
  chunkstate<<<dim3(NC, NBH), 256, 0, stream>>>(X, U, GS);
  scanS     <<<256, 256, 0, stream>>>(GS);
  retention2<<<dim3(NC, NBH), 256, 0, stream>>>(X, U, GS, Rb);

  // Gate: G = swish(q @ Wg + bg).  Grid 16x64 = 1024 blocks.
  gemm128<<<dim3(16, 64, 1), 256, 0, stream>>>(Aq, DIM, WgT, DIM, DIM, bg, 1,
                                               Gg, 0, adtq, /*obf*/1, flag);

  // GroupNorm + beta, gated; in-place U over G
  gn_gate<<<dim3(BATCH * SEQ, 1, 1), 256, 0, stream>>>(Rb, beta, Gg, flag);

  // out = U @ Wo + bo.  A=U is OUR bf16 buffer (adt=1), out fp32 per flag.
  gemm128<<<dim3(16, 64, 1), 256, 0, stream>>>(Gg, DIM, WoT, DIM, DIM, bo, 0,
                                               d_out, 0, /*adt*/1, /*obf*/2, flag);
}

// Round 10
// 290.237 us; speedup vs baseline: 1.1338x; 1.1338x over previous
//
#include <hip/hip_runtime.h>

// ---------------------------------------------------------------------------
// MultiScaleRetention on MI355X (gfx950).  Harness contract: inputs fp32,
// d_out read as fp32; detect() keeps it robust to a bf16 harness variant.
// Internal buffers are ALWAYS bf16 (r5 lesson).
//
// r6 chunkwise-state retention; r7 fine-chunk colsum scan; r9 wtrans bf16
// [N][K] weights; r11 XCD swizzle + occupancy; r12 gload_lds GEMM staging +
// coalesced epilogues; r13 BN=64 GEMM grid + retention2 gload/async-V (296us).
// r14 POST-MORTEM (329us, REVERTED): retention2/chunkstate occupancy work
// was useless — their 512-block grids cap residency at 2 blocks/CU no matter
// the LDS — while the S-half staging serialized gl_lds->barrier->MFMA on the
// critical path (exposed latency).  RULE: check min(grid/256, LDS-cap,
// VGPR-cap) BEFORE restructuring for occupancy.
// r15: exact r13 revert + merge the two 1024x1024 wtrans launches (z picks
// Wg/Wo) to save one launch.
//
// ws ~38 MB: flag | X 16.8MB | U 256KB | WqkvT 256KB | WgT 2MB | WoT 2MB |
// qb 16.8MB (optional).  d_out: [0,16MB) Rb; [16,32MB) Carry then G/S.
// ---------------------------------------------------------------------------

constexpr int SEQ  = 2048;
constexpr int BATCH= 4;
constexpr int DIM  = 1024;
constexpr int HDIM = 128;
constexpr int NH   = 8;
constexpr int NBH  = BATCH * NH;   // 32
constexpr int NC   = 16;           // chunks of 128 along SEQ (state path)
constexpr int CCH  = 32;           // fine chunk for the colsum scan
constexpr int NCC  = SEQ / CCH;    // 64

typedef __bf16 bf16x8 __attribute__((ext_vector_type(8)));
typedef float  f32x4  __attribute__((ext_vector_type(4)));

__device__ __forceinline__ f32x4 mfma16(bf16x8 a, bf16x8 b, f32x4 c) {
  return __builtin_amdgcn_mfma_f32_16x16x32_bf16(a, b, c, 0, 0, 0);
}

__device__ __forceinline__ float bf2f(unsigned short u) {
  return __builtin_bit_cast(float, (unsigned int)u << 16);
}
__device__ __forceinline__ unsigned short f2bf(float f) {
  unsigned int x = __builtin_bit_cast(unsigned int, f);
  x += 0x7fffu + ((x >> 16) & 1u);   // RNE (finite inputs)
  return (unsigned short)(x >> 16);
}

// XOR-swizzled LDS element index for bf16 tiles. RS = row stride (64 or 128).
// Col-block permutation cb -> (cb&8)|((cb^(row>>1))&7) is an involution.
__device__ __forceinline__ int swz(int row, int col, int RS) {
  int cb  = col >> 3;
  int scb = (cb & ~7) | ((cb ^ (row >> 1)) & 7);
  return row * RS + scb * 8 + (col & 7);
}

// global -> LDS direct 16B load (dest = wave-uniform base + lane*16)
typedef const __attribute__((address_space(1))) unsigned int* gas_t;
typedef __attribute__((address_space(3))) unsigned int* las_t;
__device__ __forceinline__ void gl_lds16(const unsigned short* g, unsigned short* l) {
  __builtin_amdgcn_global_load_lds((gas_t)g, (las_t)l, 16, 0, 0);
}

// Pack 8 floats -> 8 bf16 (uint4)
__device__ __forceinline__ uint4 pack8(float4 a, float4 b) {
  uint4 o;
  o.x = (unsigned int)f2bf(a.x) | ((unsigned int)f2bf(a.y) << 16);
  o.y = (unsigned int)f2bf(a.z) | ((unsigned int)f2bf(a.w) << 16);
  o.z = (unsigned int)f2bf(b.x) | ((unsigned int)f2bf(b.y) << 16);
  o.w = (unsigned int)f2bf(b.z) | ((unsigned int)f2bf(b.w) << 16);
  return o;
}

// ---------------------------------------------------------------------------
// detect: flag=1 -> inputs bf16; flag=0 -> inputs fp32 (measured: 0 here).
// ---------------------------------------------------------------------------
__global__ void detect(const unsigned short* __restrict__ q, int* __restrict__ flag)
{
  int lane = threadIdx.x;              // 64
  int sane = 0;
  for (int i = lane; i < 1024; i += 64) {
    int e = (q[i] >> 7) & 0xFF;
    sane += (e >= 100 && e <= 140) ? 1 : 0;
  }
  #pragma unroll
  for (int o = 1; o < 64; o <<= 1) sane += __shfl_xor(sane, o);
  if (lane == 0) flag[0] = (sane >= 900) ? 1 : 0;
}

// ---------------------------------------------------------------------------
// qbf: qb = bf16(q), vectorized.  One uint4 (8 bf16) out per thread.
// ---------------------------------------------------------------------------
__global__ __launch_bounds__(256) void qbf(const void* __restrict__ q,
    unsigned short* __restrict__ qb, const int* __restrict__ dflag)
{
  const int idx = blockIdx.x * 256 + threadIdx.x;   // 1,048,576 granules of 8
  if (dflag[0]) {
    ((uint4*)qb)[idx] = ((const uint4*)q)[idx];
  } else {
    float4 a = ((const float4*)q)[2 * idx];
    float4 b = ((const float4*)q)[2 * idx + 1];
    ((uint4*)qb)[idx] = pack8(a, b);
  }
}

// ---------------------------------------------------------------------------
// wtrans: dst[n][k] = bf16(src[k][n]) for one (rows x cols) matrix, 64x64 LDS
// tiles.  blockIdx.z selects a matrix slice: src = srcA slice z, unless
// srcB != null, in which case z=0 -> srcA, z=1 -> srcB (dstB likewise) —
// lets Wg and Wo share one launch.
// ---------------------------------------------------------------------------
__global__ __launch_bounds__(256) void wtrans(const void* __restrict__ srcA,
    unsigned short* __restrict__ dstA, const void* __restrict__ srcB,
    unsigned short* __restrict__ dstB, int rows, int cols,
    const int* __restrict__ dflag)
{
  __shared__ float tile[64][65];
  const int isbf = dflag[0];
  const void* src;
  unsigned short* dst;
  size_t moff;
  if (srcB) {
    src = blockIdx.z ? srcB : srcA;
    dst = blockIdx.z ? dstB : dstA;
    moff = 0;
  } else {
    src = srcA;
    dst = dstA;
    moff = (size_t)blockIdx.z * rows * cols;
  }
  const int r0 = blockIdx.y * 64, c0 = blockIdx.x * 64;
  const int tr = threadIdx.x >> 4;          // 0..15
  const int tc = (threadIdx.x & 15) * 4;    // 0,4,..,60

  #pragma unroll
  for (int rr = 0; rr < 64; rr += 16) {
    int r = r0 + rr + tr;
    if (isbf) {
      const unsigned short* s = (const unsigned short*)src + moff + (size_t)r * cols + c0 + tc;
      tile[rr + tr][tc + 0] = bf2f(s[0]);
      tile[rr + tr][tc + 1] = bf2f(s[1]);
      tile[rr + tr][tc + 2] = bf2f(s[2]);
      tile[rr + tr][tc + 3] = bf2f(s[3]);
    } else {
      float4 v = *(const float4*)((const float*)src + moff + (size_t)r * cols + c0 + tc);
      tile[rr + tr][tc + 0] = v.x;
      tile[rr + tr][tc + 1] = v.y;
      tile[rr + tr][tc + 2] = v.z;
      tile[rr + tr][tc + 3] = v.w;
    }
  }
  __syncthreads();

  const int n  = threadIdx.x >> 2;          // 0..63 (local dst row = src col)
  const int kg = (threadIdx.x & 3) * 16;    // 0,16,32,48
  unsigned int ov[8];
  #pragma unroll
  for (int j = 0; j < 8; ++j) {
    unsigned short lo = f2bf(tile[kg + 2 * j + 0][n]);
    unsigned short hi = f2bf(tile[kg + 2 * j + 1][n]);
    ov[j] = (unsigned int)lo | ((unsigned int)hi << 16);
  }
  unsigned short* d = dst + moff + (size_t)(c0 + n) * rows + r0 + kg;
  ((uint4*)d)[0] = make_uint4(ov[0], ov[1], ov[2], ov[3]);
  ((uint4*)d)[1] = make_uint4(ov[4], ov[5], ov[6], ov[7]);
}

// ---------------------------------------------------------------------------
// 128x64-tile MFMA GEMM, BK=64 (r13: BN=64, grid 1024 = 4 blocks/CU).
// A: M x K (lda); adt 0=fp32 reg-staged, 1=bf16 gload_lds, 2=per input flag.
// B: ALWAYS internal bf16 [N][K] (ldb = K stride), gload_lds staged.
// gload staging: LDS linear dest (wave base + lane*16), global source
// pre-swizzled per lane so swz() reads stay valid.
// mode 0: XCD-bijective block swizzle; bf16 out LDS-staged, fp32 out direct.
// mode 1 (head proj): z=head; A += z*128 cols; B += z*128*128; out bf16 ->
//   X[(b*8+z)*SEQ+s][HDIM], LDS-staged.
// ---------------------------------------------------------------------------
__global__ __launch_bounds__(256, 4) void gemm128(
    const void* __restrict__ A, int lda,
    const unsigned short* __restrict__ B, int ldb, int K,
    const void* __restrict__ bias, int act,
    void* __restrict__ out, int mode, int adt, int obf,
    const int* __restrict__ dflag)
{
  __shared__ __align__(16) unsigned short As[128 * 64];   // 16KB
  __shared__ __align__(16) unsigned short Bs[64 * 64];    // 8KB
  const int isbf = dflag[0];
  const int abf  = (adt == 1) || (adt == 2 && isbf);   // A is bf16?
  const int tid  = threadIdx.x;
  const int lane = tid & 63;
  const int w    = tid >> 6;
  const int wy   = w >> 1, wx = w & 1;
  const int m15  = lane & 15, qd = lane >> 4;
  // gload staging geometry
  const int w8  = w * 8;          // wave row base within a 32-row slab
  const int lr  = lane >> 3;      // row within wave slab (0..7)
  const int scb = lane & 7;       // dest col-block (linear LDS)

  int bx = blockIdx.x, by = blockIdx.y;
  if (mode == 0) {
    // XCD-bijective remap: XCD k owns a contiguous M-chunk.
    int nwg = gridDim.x * gridDim.y;   // 16*64 = 1024
    int lin = by * gridDim.x + bx;
    int qq = nwg >> 3, rr = nwg & 7;
    int xcd = lin & 7, idx = lin >> 3;
    int wg = (xcd < rr) ? xcd * (qq + 1) + idx
                        : rr * (qq + 1) + (xcd - rr) * qq + idx;
    bx = wg % gridDim.x;
    by = wg / gridDim.x;
  }

  const size_t aoff = (mode == 1) ? (size_t)blockIdx.z * 128 : 0;          // col offset
  const size_t boff = (mode == 1) ? (size_t)blockIdx.z * 128 * 128 : 0;    // elem offset
  const size_t arow = (size_t)(by * 128);
  const size_t bcol = (size_t)(bx * 64);

  f32x4 zero4 = {0.0f, 0.0f, 0.0f, 0.0f};
  f32x4 acc[4][2];
  #pragma unroll
  for (int i = 0; i < 4; ++i)
    #pragma unroll
    for (int j = 0; j < 2; ++j) acc[i][j] = zero4;

  const int kIters = K >> 6;
  for (int kt = 0; kt < kIters; ++kt) {
    __syncthreads();
    // ---- A staging: 128 rows x 64 k ----
    if (abf) {
      const unsigned short* pa = (const unsigned short*)A + aoff + arow * lda + kt * 64;
      #pragma unroll
      for (int g = 0; g < 4; ++g) {
        int r  = g * 32 + w8 + lr;
        int cb = scb ^ ((r >> 1) & 7);       // pre-swizzled source col-block
        gl_lds16(pa + (size_t)r * lda + cb * 8, &As[g * 2048 + w * 512]);
      }
    } else {
      const float* pa = (const float*)A + aoff + arow * lda + kt * 64;
      #pragma unroll
      for (int g = 0; g < 4; ++g) {
        int idx = tid + g * 256;
        int r = idx >> 3, cb = idx & 7;
        float4 f0 = *(const float4*)(pa + (size_t)r * lda + cb * 8);
        float4 f1 = *(const float4*)(pa + (size_t)r * lda + cb * 8 + 4);
        *(uint4*)&As[swz(r, cb * 8, 64)] = pack8(f0, f1);
      }
    }
    // ---- B staging: 64 rows x 64 k, [N][K] bf16, gload_lds ----
    {
      const unsigned short* pb = B + boff + bcol * (size_t)ldb + kt * 64;
      #pragma unroll
      for (int g = 0; g < 2; ++g) {
        int r  = g * 32 + w8 + lr;
        int cb = scb ^ ((r >> 1) & 7);
        gl_lds16(pb + (size_t)r * ldb + cb * 8, &Bs[g * 2048 + w * 512]);
      }
    }
    __syncthreads();
    #pragma unroll
    for (int kk = 0; kk < 2; ++kk) {
      bf16x8 af[4], bfr[2];
      #pragma unroll
      for (int mt = 0; mt < 4; ++mt)
        af[mt] = *(const bf16x8*)&As[swz(wy * 64 + mt * 16 + m15, kk * 32 + qd * 8, 64)];
      #pragma unroll
      for (int nt = 0; nt < 2; ++nt)
        bfr[nt] = *(const bf16x8*)&Bs[swz(wx * 32 + nt * 16 + m15, kk * 32 + qd * 8, 64)];
      #pragma unroll
      for (int mt = 0; mt < 4; ++mt)
        #pragma unroll
        for (int nt = 0; nt < 2; ++nt)
          acc[mt][nt] = mfma16(af[mt], bfr[nt], acc[mt][nt]);
    }
  }

  const int obf_eff = (obf == 2) ? (isbf ? 1 : 0) : obf;

  if (mode == 1 || obf_eff) {
    // bf16 output: LDS-staged coalesced epilogue ([128][64] = As, 16KB).
    __syncthreads();
    #pragma unroll
    for (int mt = 0; mt < 4; ++mt)
      #pragma unroll
      for (int nt = 0; nt < 2; ++nt) {
        int nl = wx * 32 + nt * 16 + m15;
        float bv = 0.0f;
        if (bias) {
          int n = bx * 64 + nl;
          bv = isbf ? bf2f(((const unsigned short*)bias)[n]) : ((const float*)bias)[n];
        }
        #pragma unroll
        for (int r = 0; r < 4; ++r) {
          int ml = wy * 64 + mt * 16 + qd * 4 + r;
          float v = acc[mt][nt][r] + bv;
          if (act == 1) v = v / (1.0f + __expf(-v));   // swish
          As[swz(ml, nl, 64)] = f2bf(v);
        }
      }
    __syncthreads();
    #pragma unroll
    for (int g = 0; g < 4; ++g) {
      int idx = tid + g * 256;               // 1024 granules of 16B
      int rr = idx >> 3, cbb = idx & 7;
      int m = by * 128 + rr;
      uint4 vv = *(const uint4*)&As[swz(rr, cbb * 8, 64)];
      if (mode == 1) {
        int b = m >> 11, s = m & 2047;
        size_t bh = (size_t)(b * NH + blockIdx.z);
        *(uint4*)&((unsigned short*)out)[(bh * SEQ + s) * HDIM + bx * 64 + cbb * 8] = vv;
      } else {
        *(uint4*)&((unsigned short*)out)[(size_t)m * (gridDim.x * 64) + bx * 64 + cbb * 8] = vv;
      }
    }
    return;
  }

  // fp32 output: direct stores (16 lanes x 4B = full 64B lines).
  #pragma unroll
  for (int mt = 0; mt < 4; ++mt)
    #pragma unroll
    for (int nt = 0; nt < 2; ++nt) {
      int nl = wx * 32 + nt * 16 + m15;
      int n  = bx * 64 + nl;
      float bv = 0.0f;
      if (bias) bv = isbf ? bf2f(((const unsigned short*)bias)[n]) : ((const float*)bias)[n];
      #pragma unroll
      for (int r = 0; r < 4; ++r) {
        int ml = wy * 64 + mt * 16 + qd * 4 + r;
        int m  = by * 128 + ml;
        float v = acc[mt][nt][r] + bv;
        if (act == 1) v = v / (1.0f + __expf(-v));   // swish
        ((float*)out)[(size_t)m * (gridDim.x * 64) + n] = v;
      }
    }
}

// ---------------------------------------------------------------------------
// kzcA: L[bh][cc][d] = sum_{i=0..31} g^i X[cc*32+i, d].
// ---------------------------------------------------------------------------
__global__ __launch_bounds__(128) void kzcA(const unsigned short* __restrict__ X,
                                            float* __restrict__ L)
{
  const int d  = threadIdx.x;            // 128
  const int cc = blockIdx.x;             // 64
  const int bh = blockIdx.y;             // 32
  const int h  = bh & 7;
  const float gam = 1.0f - exp2f(-5.0f - (float)h);
  const unsigned short* Xb = X + (size_t)bh * SEQ * HDIM + (size_t)cc * CCH * HDIM;
  float z = 0.0f;
  #pragma unroll
  for (int i = CCH - 1; i >= 0; --i)
    z = bf2f(Xb[(size_t)i * HDIM + d]) + gam * z;
  L[((size_t)bh * NCC + cc) * HDIM + d] = z;
}

// ---------------------------------------------------------------------------
// kzcB: in-place combine L -> Carry.  Carry[bh][cc][d] = Z_{(cc+1)*32}.
// ---------------------------------------------------------------------------
__global__ __launch_bounds__(128) void kzcB(float* __restrict__ L)
{
  const int d  = threadIdx.x;            // 128
  const int bh = blockIdx.x;             // 32
  const int h  = bh & 7;
  const float gam = 1.0f - exp2f(-5.0f - (float)h);
  const float g32 = exp2f(log2f(gam) * (float)CCH);
  float z = 0.0f;
  for (int cc = NCC - 1; cc >= 0; --cc) {
    size_t i = ((size_t)bh * NCC + cc) * HDIM + d;
    float lc = L[i];
    L[i] = z;                 // Carry[cc] = Z_{(cc+1)*32}
    z = lc + g32 * z;
  }
}

// ---------------------------------------------------------------------------
// kdot2: per (fine chunk of 32, bh) chunk-local suffix in regs, wave-reduced
// dot(X_t, Z_t) stashed in lane t; tail computed once across 32 lanes.
// Emits u_t = c1 / (sqrt(colD_t) * max(|colsum_t|,1)).
// ---------------------------------------------------------------------------
__global__ __launch_bounds__(64) void kdot2(const unsigned short* __restrict__ X,
    const float* __restrict__ Carry, float* __restrict__ U)
{
  const int lane = threadIdx.x;          // 64
  const int cc   = blockIdx.x;           // 64 fine chunks of 32
  const int bh   = blockIdx.y;
  const int h    = bh & 7;
  const float gam    = 1.0f - exp2f(-5.0f - (float)h);
  const float l2g    = log2f(gam);
  const float inv1mg = exp2f(5.0f + (float)h);          // 1/(1-g) exact
  const float c1     = 0.08838834764831845f;            // 1/sqrt(128)
  const unsigned short* Xb = X + (size_t)bh * SEQ * HDIM + (size_t)cc * CCH * HDIM;
  float2 cr = *(const float2*)(Carry + ((size_t)bh * NCC + cc) * HDIM + lane * 2);
  float z0 = 0.0f, z1 = 0.0f;
  float coeff = gam;                     // g^{(cc+1)*32 - t}
  float keep = 0.0f;
  #pragma unroll
  for (int i = 0; i < CCH; ++i) {
    const int t = CCH - 1 - i;           // descending local t
    unsigned int xu = *(const unsigned int*)(Xb + (size_t)t * HDIM + lane * 2);
    float x0 = bf2f((unsigned short)(xu & 0xffffu));
    float x1 = bf2f((unsigned short)(xu >> 16));
    z0 = x0 + gam * z0;                  // local suffix incl. x_t
    z1 = x1 + gam * z1;
    float dot = x0 * (z0 + coeff * cr.x) + x1 * (z1 + coeff * cr.y);
    #pragma unroll
    for (int o = 1; o < 64; o <<= 1) dot += __shfl_xor(dot, o);
    if (lane == t) keep = dot;
    coeff *= gam;
  }
  if (lane < CCH) {
    int tg = cc * CCH + lane;
    float colD   = (1.0f - exp2f(l2g * (float)(SEQ - tg))) * inv1mg;
    float sq     = sqrtf(colD);
    float colsum = keep * c1 / sq;
    float den    = fmaxf(fabsf(colsum), 1.0f);
    U[(size_t)bh * SEQ + tg] = c1 / (sq * den);
  }
}

// ---------------------------------------------------------------------------
// chunkstate: per (c, bh) compute G_c[d1,d2] = sum_{tl} g^{127-tl} u_t
// X[t,d1] X[t,d2], bf16 out; LDS-staged coalesced epilogue via XT halves.
// (r13 structure: 64KB LDS — grid is 512 blocks -> 2 blocks/CU by grid.)
// ---------------------------------------------------------------------------
__global__ __launch_bounds__(256, 2) void chunkstate(
    const unsigned short* __restrict__ X,
    const float* __restrict__ U,
    unsigned short* __restrict__ G)
{
  __shared__ __align__(16) unsigned short XT [16384];  // [d][t] RS=128
  __shared__ __align__(16) unsigned short XTs[16384];  // scaled copy
  const int tid  = threadIdx.x;
  const int lane = tid & 63;
  const int w    = tid >> 6;
  const int wy   = w >> 1, wx = w & 1;
  const int m15  = lane & 15, qd = lane >> 4;
  const int c    = blockIdx.x;           // 16
  const int bh   = blockIdx.y;           // 32
  const int h    = bh & 7;
  const float gam = 1.0f - exp2f(-5.0f - (float)h);
  const float l2g = log2f(gam);
  const int t0 = c * 128;
  const unsigned short* Xb = X + (size_t)bh * SEQ * HDIM;
  const float* Ub = U + (size_t)bh * SEQ;

  #pragma unroll
  for (int g = 0; g < 8; ++g) {
    int idx = tid + g * 256;             // 2048 granules: 128 t x 16 col-blocks
    int t = idx >> 4, d0 = (idx & 15) * 8;
    uint4 w4 = *(const uint4*)(Xb + (size_t)(t0 + t) * HDIM + d0);
    float wt = exp2f(l2g * (float)(127 - t)) * Ub[t0 + t];
    const unsigned short* wp = (const unsigned short*)&w4;
    #pragma unroll
    for (int j = 0; j < 8; ++j) {
      unsigned short v = wp[j];
      XT [swz(d0 + j, t, 128)] = v;
      XTs[swz(d0 + j, t, 128)] = f2bf(bf2f(v) * wt);
    }
  }
  __syncthreads();

  f32x4 zero4 = {0.0f, 0.0f, 0.0f, 0.0f};
  f32x4 acc[4][4];
  #pragma unroll
  for (int i = 0; i < 4; ++i)
    #pragma unroll
    for (int j = 0; j < 4; ++j) acc[i][j] = zero4;

  #pragma unroll
  for (int kk = 0; kk < 4; ++kk) {
    bf16x8 af[4], bfr[4];
    #pragma unroll
    for (int mt = 0; mt < 4; ++mt)
      af[mt] = *(const bf16x8*)&XTs[swz(wy * 64 + mt * 16 + m15, kk * 32 + qd * 8, 128)];
    #pragma unroll
    for (int nt = 0; nt < 4; ++nt)
      bfr[nt] = *(const bf16x8*)&XT[swz(wx * 64 + nt * 16 + m15, kk * 32 + qd * 8, 128)];
    #pragma unroll
    for (int mt = 0; mt < 4; ++mt)
      #pragma unroll
      for (int nt = 0; nt < 4; ++nt)
        acc[mt][nt] = mfma16(af[mt], bfr[nt], acc[mt][nt]);
  }

  unsigned short* Gp = G + (((size_t)bh * NC + c) << 14);
  #pragma unroll
  for (int half = 0; half < 2; ++half) {
    __syncthreads();
    if (wy == half) {
      #pragma unroll
      for (int mt = 0; mt < 4; ++mt)
        #pragma unroll
        for (int nt = 0; nt < 4; ++nt) {
          int d2 = wx * 64 + nt * 16 + m15;
          #pragma unroll
          for (int r = 0; r < 4; ++r) {
            int dl = mt * 16 + qd * 4 + r;
            XT[swz(dl, d2, 128)] = f2bf(acc[mt][nt][r]);
          }
        }
    }
    __syncthreads();
    #pragma unroll
    for (int g = 0; g < 4; ++g) {
      int idx = tid + g * 256;              // 1024 granules of 16B
      int rr = idx >> 4, cbb = idx & 15;
      *(uint4*)&Gp[(size_t)(half * 64 + rr) * 128 + cbb * 8] =
          *(const uint4*)&XT[swz(rr, cbb * 8, 128)];
    }
  }
}

// ---------------------------------------------------------------------------
// scanS: in-place prefix scan over chunks:  S_c = g^128 * S_{c-1} + G_c.
// ---------------------------------------------------------------------------
__global__ __launch_bounds__(256) void scanS(unsigned short* __restrict__ GS)
{
  int gid = blockIdx.x * 256 + threadIdx.x;    // 65536 total
  int bh = gid >> 11;
  int e8 = (gid & 2047) << 3;
  int h  = bh & 7;
  float gam  = 1.0f - exp2f(-5.0f - (float)h);
  float g128 = exp2f(log2f(gam) * 128.0f);
  float s[8];
  #pragma unroll
  for (int j = 0; j < 8; ++j) s[j] = 0.0f;
  unsigned short* base = GS + ((size_t)bh << 18) + e8;   // bh * 16 * 16384
  #pragma unroll
  for (int c = 0; c < NC; ++c) {
    uint4 v = *(uint4*)(base + ((size_t)c << 14));
    const unsigned short* wp = (const unsigned short*)&v;
    #pragma unroll
    for (int j = 0; j < 8; ++j) s[j] = g128 * s[j] + bf2f(wp[j]);
    uint4 o;
    unsigned int* op = (unsigned int*)&o;
    op[0] = (unsigned int)f2bf(s[0]) | ((unsigned int)f2bf(s[1]) << 16);
    op[1] = (unsigned int)f2bf(s[2]) | ((unsigned int)f2bf(s[3]) << 16);
    op[2] = (unsigned int)f2bf(s[4]) | ((unsigned int)f2bf(s[5]) << 16);
    op[3] = (unsigned int)f2bf(s[6]) | ((unsigned int)f2bf(s[7]) << 16);
    *(uint4*)(base + ((size_t)c << 14)) = o;
  }
}

// ---------------------------------------------------------------------------
// retention2: per (chunk c, bh), UNIFORM work (r13 structure, 64KB LDS —
// grid 512 -> 2 blocks/CU by grid, LDS not binding):
//   cross: O = diag(g^{sl+1}) * X_s @ S_{c-1}; local masked triangle via LDS.
// Qs/SB staged via global_load_lds (pre-swizzled source); VsT global loads
// issued EARLY (T14): th=0 at kernel entry, th=1 during th=0 P/PV.
// ---------------------------------------------------------------------------
__global__ __launch_bounds__(256, 2) void retention2(
    const unsigned short* __restrict__ X,
    const float* __restrict__ U,
    const unsigned short* __restrict__ S,
    unsigned short* __restrict__ R)
{
  __shared__ __align__(16) unsigned short Qs[16384];
  __shared__ __align__(16) unsigned short SB[16384];

  const int tid  = threadIdx.x;
  const int lane = tid & 63;
  const int w    = tid >> 6;
  const int wy   = w >> 1, wx = w & 1;
  const int m15  = lane & 15, qd = lane >> 4;
  const int c    = blockIdx.x;           // 16
  const int bh   = blockIdx.y;           // 32
  const int h    = bh & 7;
  const int b    = bh >> 3;
  const float gam = 1.0f - exp2f(-5.0f - (float)h);
  const float l2g = log2f(gam);
  const int sbase = c * 128;
  const unsigned short* Xb = X + (size_t)bh * SEQ * HDIM;
  const float* Ub = U + (size_t)bh * SEQ;

  // ---- Qs + SB staging via gload_lds (pre-swizzled source) ----
  {
    const int lr4 = lane >> 4;           // 0..3
    const int cbd = lane & 15;           // dest col-block
    #pragma unroll
    for (int g = 0; g < 8; ++g) {
      int r   = g * 16 + w * 4 + lr4;
      int cbs = (cbd & 8) | ((cbd ^ (r >> 1)) & 7);
      gl_lds16(Xb + (size_t)(sbase + r) * HDIM + cbs * 8, &Qs[(g * 16 + w * 4) * 128]);
    }
    if (c > 0) {
      const unsigned short* Sp = S + (((size_t)bh * NC + (c - 1)) << 14);
      #pragma unroll
      for (int g = 0; g < 8; ++g) {
        int r   = g * 16 + w * 4 + lr4;
        int cbs = (cbd & 8) | ((cbd ^ (r >> 1)) & 7);
        gl_lds16(Sp + (size_t)r * 128 + cbs * 8, &SB[(g * 16 + w * 4) * 128]);
      }
    }
  }
  // T14 early issue: th=0 V tile into registers (overlaps staging + cross).
  uint4 rvb[2][4];
  #pragma unroll
  for (int g = 0; g < 4; ++g) {
    int idx = tid + g * 256;
    int t = idx & 63, d0 = (idx >> 6) * 8;
    rvb[0][g] = *(const uint4*)(Xb + (size_t)(sbase + t) * HDIM + d0);
  }
  __syncthreads();

  bf16x8 aq[4][4];
  #pragma unroll
  for (int mt = 0; mt < 4; ++mt)
    #pragma unroll
    for (int kk = 0; kk < 4; ++kk)
      aq[mt][kk] = *(const bf16x8*)&Qs[swz(wy * 64 + mt * 16 + m15, kk * 32 + qd * 8, 128)];

  float crowL[16];                       // g^{sl}, sl = chunk-local row
  #pragma unroll
  for (int mt = 0; mt < 4; ++mt)
    #pragma unroll
    for (int r = 0; r < 4; ++r)
      crowL[mt * 4 + r] = exp2f(l2g * (float)(wy * 64 + mt * 16 + qd * 4 + r));

  f32x4 zero4 = {0.0f, 0.0f, 0.0f, 0.0f};
  f32x4 oacc[4][4];
  #pragma unroll
  for (int i = 0; i < 4; ++i)
    #pragma unroll
    for (int j = 0; j < 4; ++j) oacc[i][j] = zero4;

  if (c > 0) {                           // cross term: X_s @ S_{c-1}
    #pragma unroll
    for (int kk = 0; kk < 4; ++kk) {
      bf16x8 bs[4];                      // B[n=d2][k=d1] = S[d1][d2] = S[d2][d1]
      #pragma unroll
      for (int nt = 0; nt < 4; ++nt)
        bs[nt] = *(const bf16x8*)&SB[swz(wx * 64 + nt * 16 + m15, kk * 32 + qd * 8, 128)];
      #pragma unroll
      for (int mt = 0; mt < 4; ++mt)
        #pragma unroll
        for (int nt = 0; nt < 4; ++nt)
          oacc[mt][nt] = mfma16(aq[mt][kk], bs[nt], oacc[mt][nt]);
    }
    #pragma unroll
    for (int mt = 0; mt < 4; ++mt) {     // scale cross by g^{sl+1}
      #pragma unroll
      for (int r = 0; r < 4; ++r) {
        float f = crowL[mt * 4 + r] * gam;
        #pragma unroll
        for (int nt = 0; nt < 4; ++nt) oacc[mt][nt][r] *= f;
      }
    }
  }

  unsigned short* VsT = SB;              // 128 d x 64 t, RS=64 (16KB)
  unsigned short* Ps  = SB + 8192;       // 128 s x 64 t, RS=64 (16KB)

  #pragma unroll
  for (int th = 0; th < 2; ++th) {
    const int t0 = th * 64;
    // local QK^T for this t-half (reads only Qs)
    f32x4 pacc[4][2];
    #pragma unroll
    for (int i = 0; i < 4; ++i) { pacc[i][0] = zero4; pacc[i][1] = zero4; }
    #pragma unroll
    for (int kk = 0; kk < 4; ++kk) {
      bf16x8 bk[2];
      #pragma unroll
      for (int nt = 0; nt < 2; ++nt)
        bk[nt] = *(const bf16x8*)&Qs[swz(t0 + wx * 32 + nt * 16 + m15, kk * 32 + qd * 8, 128)];
      #pragma unroll
      for (int mt = 0; mt < 4; ++mt)
        #pragma unroll
        for (int nt = 0; nt < 2; ++nt)
          pacc[mt][nt] = mfma16(aq[mt][kk], bk[nt], pacc[mt][nt]);
    }
    __syncthreads();                     // SB readers (cross / prev PV) done

    // VsT write from pre-loaded registers: VsT[d][t] = X[t][d]
    #pragma unroll
    for (int g = 0; g < 4; ++g) {
      int idx = tid + g * 256;
      int t = idx & 63, d0 = (idx >> 6) * 8;
      const unsigned short* wp = (const unsigned short*)&rvb[th][g];
      #pragma unroll
      for (int j = 0; j < 8; ++j)
        VsT[swz(d0 + j, t, 64)] = wp[j];
    }
    if (th == 0) {                       // issue th=1 V loads (hide under P/PV)
      #pragma unroll
      for (int g = 0; g < 4; ++g) {
        int idx = tid + g * 256;
        int t = idx & 63, d0 = (idx >> 6) * 8;
        rvb[1][g] = *(const uint4*)(Xb + (size_t)(sbase + 64 + t) * HDIM + d0);
      }
    }
    // P = mask(s>=t) * pacc * g^{s-t} * u_t  -> bf16 LDS
    #pragma unroll
    for (int nt = 0; nt < 2; ++nt) {
      int tloc = t0 + wx * 32 + nt * 16 + m15;
      float cf = exp2f(-l2g * (float)tloc) * Ub[sbase + tloc];   // g^{-tloc} u_t
      #pragma unroll
      for (int mt = 0; mt < 4; ++mt)
        #pragma unroll
        for (int r = 0; r < 4; ++r) {
          int sl = wy * 64 + mt * 16 + qd * 4 + r;
          float v = (sl >= tloc) ? pacc[mt][nt][r] * crowL[mt * 4 + r] * cf : 0.0f;
          Ps[swz(sl, tloc - t0, 64)] = f2bf(v);
        }
    }
    __syncthreads();
    // O += P @ V
    #pragma unroll
    for (int kk = 0; kk < 2; ++kk) {
      bf16x8 ap[4], bv[4];
      #pragma unroll
      for (int mt = 0; mt < 4; ++mt)
        ap[mt] = *(const bf16x8*)&Ps[swz(wy * 64 + mt * 16 + m15, kk * 32 + qd * 8, 64)];
      #pragma unroll
      for (int nt = 0; nt < 4; ++nt)
        bv[nt] = *(const bf16x8*)&VsT[swz(wx * 64 + nt * 16 + m15, kk * 32 + qd * 8, 64)];
      #pragma unroll
      for (int mt = 0; mt < 4; ++mt)
        #pragma unroll
        for (int nt = 0; nt < 4; ++nt)
          oacc[mt][nt] = mfma16(ap[mt], bv[nt], oacc[mt][nt]);
    }
  }

  // --- LDS-staged coalesced O write (SB free after last PV reads) ---
  __syncthreads();
  #pragma unroll
  for (int mt = 0; mt < 4; ++mt)
    #pragma unroll
    for (int nt = 0; nt < 4; ++nt) {
      int n = wx * 64 + nt * 16 + m15;
      #pragma unroll
      for (int r = 0; r < 4; ++r) {
        int sl = wy * 64 + mt * 16 + qd * 4 + r;
        SB[swz(sl, n, 128)] = f2bf(oacc[mt][nt][r]);
      }
    }
  __syncthreads();
  #pragma unroll
  for (int g = 0; g < 8; ++g) {
    int idx = tid + g * 256;               // 2048 granules of 16B
    int rr = idx >> 4, cbb = idx & 15;
    *(uint4*)&R[(size_t)(b * SEQ + sbase + rr) * DIM + h * HDIM + cbb * 8] =
        *(const uint4*)&SB[swz(rr, cbb * 8, 128)];
  }
}

// ---------------------------------------------------------------------------
// GroupNorm(32 groups of 32 channels) + beta (per-flag dtype), gated; U
// written IN PLACE over G (ours, bf16).
// ---------------------------------------------------------------------------
__global__ __launch_bounds__(256) void gn_gate(const unsigned short* __restrict__ R,
    const void* __restrict__ beta, unsigned short* __restrict__ GU,
    const int* __restrict__ dflag)
{
  const int isbf = dflag[0];
  const int row = blockIdx.x;
  const int t   = threadIdx.x;
  uint2 xv = *(const uint2*)(R + (size_t)row * DIM + t * 4);
  float x0 = bf2f((unsigned short)(xv.x & 0xffffu)), x1 = bf2f((unsigned short)(xv.x >> 16));
  float x2 = bf2f((unsigned short)(xv.y & 0xffffu)), x3 = bf2f((unsigned short)(xv.y >> 16));
  float s  = x0 + x1 + x2 + x3;
  float ss = x0 * x0 + x1 * x1 + x2 * x2 + x3 * x3;
  #pragma unroll
  for (int m = 1; m <= 4; m <<= 1) {
    s  += __shfl_xor(s, m, 8);
    ss += __shfl_xor(ss, m, 8);
  }
  float mean = s * (1.0f / 32.0f);
  float var  = ss * (1.0f / 32.0f) - mean * mean;
  float rstd = rsqrtf(var + 1e-3f);
  float b0, b1, b2, b3;
  if (isbf) {
    uint2 bv = *(const uint2*)((const unsigned short*)beta + t * 4);
    b0 = bf2f((unsigned short)(bv.x & 0xffffu)); b1 = bf2f((unsigned short)(bv.x >> 16));
    b2 = bf2f((unsigned short)(bv.y & 0xffffu)); b3 = bf2f((unsigned short)(bv.y >> 16));
  } else {
    float4 bv = *(const float4*)((const float*)beta + t * 4);
    b0 = bv.x; b1 = bv.y; b2 = bv.z; b3 = bv.w;
  }
  uint2 gv = *(const uint2*)(GU + (size_t)row * DIM + t * 4);
  float g0 = bf2f((unsigned short)(gv.x & 0xffffu)), g1 = bf2f((unsigned short)(gv.x >> 16));
  float g2 = bf2f((unsigned short)(gv.y & 0xffffu)), g3 = bf2f((unsigned short)(gv.y >> 16));
  unsigned short u0 = f2bf(((x0 - mean) * rstd + b0) * g0);
  unsigned short u1 = f2bf(((x1 - mean) * rstd + b1) * g1);
  unsigned short u2 = f2bf(((x2 - mean) * rstd + b2) * g2);
  unsigned short u3 = f2bf(((x3 - mean) * rstd + b3) * g3);
  uint2 o;
  o.x = (unsigned int)u0 | ((unsigned int)u1 << 16);
  o.y = (unsigned int)u2 | ((unsigned int)u3 << 16);
  *(uint2*)(GU + (size_t)row * DIM + t * 4) = o;
}

// ---------------------------------------------------------------------------
extern "C" void kernel_launch(void* const* d_in, const int* in_sizes, int n_in,
                              void* d_out, int out_size, void* d_ws, size_t ws_size,
                              hipStream_t stream)
{
  (void)in_sizes; (void)n_in; (void)out_size;
  const void* q    = d_in[0];
  // d_in[1]=k, d_in[2]=v unused (reference uses q for Q,K,V)
  const void* Wqkv = d_in[3];
  const void* Wg   = d_in[4];
  const void* bg   = d_in[5];
  const void* Wo   = d_in[6];
  const void* bo   = d_in[7];
  const void* beta = d_in[8];

  char* p = (char*)d_ws;
  auto take = [&](size_t bytes) { char* r = p; p += (bytes + 255) & ~(size_t)255; return r; };
  int*  flag = (int*)take(256);
  unsigned short* X  = (unsigned short*)take((size_t)NBH * SEQ * HDIM * 2);  // 16.8 MB
  float* U     = (float*)take((size_t)NBH * SEQ * 4);                        // 256 KB
  unsigned short* WqkvT = (unsigned short*)take((size_t)NH * HDIM * HDIM * 2);   // 256 KB
  unsigned short* WgT   = (unsigned short*)take((size_t)DIM * DIM * 2);          // 2 MB
  unsigned short* WoT   = (unsigned short*)take((size_t)DIM * DIM * 2);          // 2 MB
  // Optional bf16 copy of q (enables gload_lds A staging everywhere).
  size_t qbBytes = (size_t)BATCH * SEQ * DIM * 2;                            // 16.8 MB
  unsigned short* qb = (unsigned short*)take(qbBytes);
  const bool useQb = ((size_t)(p - (char*)d_ws) <= ws_size);
  // Aliases (stream-ordered lifetimes):
  unsigned short* Rb = (unsigned short*)d_out;                          // [0,16MB)
  unsigned short* GS = (unsigned short*)((char*)d_out + (size_t)16 * 1024 * 1024); // [16,32MB)
  float* Carry = (float*)GS;   // 1MB at GS head, dead before chunkstate
  unsigned short* Gg = X;      // gate gemm output after retention2

  detect<<<1, 64, 0, stream>>>((const unsigned short*)q, flag);

  // Pre-transpose + convert weights to bf16 [N][K]; optional q -> bf16.
  // Wg and Wo share one launch (z picks the matrix).
  wtrans<<<dim3(16, 16, 2), 256, 0, stream>>>(Wg, WgT, Wo, WoT, DIM, DIM, flag);
  wtrans<<<dim3(2, 2, NH),  256, 0, stream>>>(Wqkv, WqkvT, nullptr, nullptr,
                                              HDIM, HDIM, flag);
  if (useQb)
    qbf<<<4096, 256, 0, stream>>>(q, qb, flag);

  const void* Aq = useQb ? (const void*)qb : q;
  const int   adtq = useQb ? 1 : 2;

  // X = q_h @ W_h per head (N=128 per head -> 2 N-blocks of 64).
  gemm128<<<dim3(2, 64, NH), 256, 0, stream>>>(Aq, DIM, WqkvT, HDIM, HDIM,
                                               nullptr, 0, X, 1, adtq, /*obf*/1, flag);

  // Column-normalizer: 32-step local decayed sums, combine, per-chunk dot.
  kzcA <<<dim3(NCC, NBH), 128, 0, stream>>>(X, Carry);
  kzcB <<<NBH, 128, 0, stream>>>(Carry);
  kdot2<<<dim3(NCC, NBH), 64, 0, stream>>>(X, Carry, U);

  // Chunkwise state path: G_c -> (scan) -> S_c, then uniform retention blocks.
  chunkstate<<<dim3(NC, NBH), 256, 0, stream>>>(X, U, GS);
  scanS     <<<256, 256, 0, stream>>>(GS);
  retention2<<<dim3(NC, NBH), 256, 0, stream>>>(X, U, GS, Rb);

  // Gate: G = swish(q @ Wg + bg).  Grid 16x64 = 1024 blocks.
  gemm128<<<dim3(16, 64, 1), 256, 0, stream>>>(Aq, DIM, WgT, DIM, DIM, bg, 1,
                                               Gg, 0, adtq, /*obf*/1, flag);

  // GroupNorm + beta, gated; in-place U over G
  gn_gate<<<dim3(BATCH * SEQ, 1, 1), 256, 0, stream>>>(Rb, beta, Gg, flag);

  // out = U @ Wo + bo.  A=U is OUR bf16 buffer (adt=1), out fp32 per flag.
  gemm128<<<dim3(16, 64, 1), 256, 0, stream>>>(Gg, DIM, WoT, DIM, DIM, bo, 0,
                                               d_out, 0, /*adt*/1, /*obf*/2, flag);
}